// Round 1
// baseline (5338.786 us; speedup 1.0000x reference)
//
#include <hip/hip_runtime.h>
#include <hip/hip_bf16.h>
#include <math.h>

#define NN 50000
#define NE 100000
#define FN 128
#define FE 16
#define HD 64
#define OUTD 32
#define NG 64
#define ZK 65           // 64 edge-MLP features + 1 bias slot (z=1)
#define KTOT (ZK*HD)    // 4160

static __device__ __forceinline__ void fma4(float4& a, float s, const float4 b) {
    a.x += s*b.x; a.y += s*b.y; a.z += s*b.z; a.w += s*b.w;
}
static __device__ __forceinline__ float dot4(const float4 a, const float4 b) {
    return a.x*b.x + a.y*b.y + a.z*b.z + a.w*b.w;
}

// W2x[(k0*64+j)*64 + i] = k0<64 ? W_e2[k0*4096 + i*64 + j] : b_e2[i*64+j]
__global__ void k_build_w2x(const float* __restrict__ W_e2, const float* __restrict__ b_e2,
                            float* __restrict__ W2x) {
    int idx = blockIdx.x*256 + threadIdx.x;
    if (idx >= KTOT*HD) return;
    int i = idx & 63;
    int r = idx >> 6;          // r = k0*64 + j
    int k0 = r >> 6, j = r & 63;
    W2x[idx] = (k0 < 64) ? W_e2[k0*4096 + i*64 + j] : b_e2[i*64 + j];
}

// h[n,o] = b_enc[o] + sum_f x[n,f] * W_enc[f*64+o]
__global__ void k_encode(const float* __restrict__ x, const float* __restrict__ W,
                         const float* __restrict__ b, float* __restrict__ h) {
    int idx = blockIdx.x*256 + threadIdx.x;
    int o = idx & 63, n = idx >> 6;
    if (n >= NN) return;
    const float* xr = x + n*FN;
    float acc = b[o];
    #pragma unroll 8
    for (int f = 0; f < FN; f++) acc += xr[f] * W[f*64 + o];
    h[idx] = acc;
}

// z[e,k] = relu(b_e1[k] + sum_f ea[e,f]*W_e1[f*64+k]); z[e,64] = 1
__global__ void k_edgez(const float* __restrict__ ea, const float* __restrict__ W,
                        const float* __restrict__ b, float* __restrict__ z) {
    int idx = blockIdx.x*256 + threadIdx.x;
    int k = idx & 63, e = idx >> 6;
    if (e >= NE) return;
    const float* er = ea + e*FE;
    float acc = b[k];
    #pragma unroll
    for (int f = 0; f < FE; f++) acc += er[f] * W[f*64 + k];
    z[e*ZK + k] = fmaxf(acc, 0.f);
    if (k == 0) z[e*ZK + 64] = 1.0f;
}

// Fused message GEMM + scatter: block = 64 edges, msg[e,i] = sum_{k0,j} z[e,k0]*hs[e,j]*W2x[(k0*64+j)*64+i]
// then atomicAdd into m_agg[dst[e]].
__global__ __launch_bounds__(256)
void k_message(const float* __restrict__ z, const float* __restrict__ h,
               const int* __restrict__ edge_index, const float* __restrict__ W2x,
               float* __restrict__ m_agg) {
    __shared__ float zs[64*ZK];                 // [el][65], 65 odd -> conflict-free
    __shared__ float hs[64*68];                 // [el][j] padded to 68 (2-way max)
    __shared__ __align__(16) float wblk[64*64]; // [j][i] for current k0
    int t = threadIdx.x;
    int e0 = blockIdx.x * 64;

    for (int idx = t; idx < 64*ZK; idx += 256) {
        int el = idx / ZK;
        int e = e0 + el; if (e >= NE) e = NE-1;
        zs[idx] = z[e*ZK + (idx - el*ZK)];
    }
    #pragma unroll
    for (int rep = 0; rep < 16; rep++) {
        int idx = rep*256 + t;
        int el = idx >> 6, j = idx & 63;
        int e = e0 + el; if (e >= NE) e = NE-1;
        int s = edge_index[e];                  // src = edge_index[0][e]
        hs[el*68 + j] = h[s*64 + j];
    }

    int el = t >> 2, iq = t & 3;                // thread owns edge el, outputs i = iq*16..iq*16+15
    float4 acc0 = make_float4(0,0,0,0), acc1 = acc0, acc2 = acc0, acc3 = acc0;
    const float* zrow = zs + el*ZK;
    const float* hrow = hs + el*68;

    for (int k0 = 0; k0 < ZK; k0++) {
        __syncthreads();
        const float* wsrc = W2x + k0*4096;
        #pragma unroll
        for (int rep = 0; rep < 16; rep++) {
            int idx = rep*256 + t;
            wblk[idx] = wsrc[idx];
        }
        __syncthreads();
        float pe = zrow[k0];
        #pragma unroll 4
        for (int j = 0; j < 64; j++) {
            float pj = pe * hrow[j];
            const float4* wr = (const float4*)(wblk + j*64 + iq*16);
            fma4(acc0, pj, wr[0]);
            fma4(acc1, pj, wr[1]);
            fma4(acc2, pj, wr[2]);
            fma4(acc3, pj, wr[3]);
        }
    }
    int e = e0 + el;
    if (e < NE) {
        int d = edge_index[NE + e];             // dst = edge_index[1][e]
        float* p = m_agg + d*64 + iq*16;
        atomicAdd(p+0,  acc0.x); atomicAdd(p+1,  acc0.y); atomicAdd(p+2,  acc0.z); atomicAdd(p+3,  acc0.w);
        atomicAdd(p+4,  acc1.x); atomicAdd(p+5,  acc1.y); atomicAdd(p+6,  acc1.z); atomicAdd(p+7,  acc1.w);
        atomicAdd(p+8,  acc2.x); atomicAdd(p+9,  acc2.y); atomicAdd(p+10, acc2.z); atomicAdd(p+11, acc2.w);
        atomicAdd(p+12, acc3.x); atomicAdd(p+13, acc3.y); atomicAdd(p+14, acc3.z); atomicAdd(p+15, acc3.w);
    }
}

// GRU cell: block = 4 nodes x 64 outputs. torch gate order: rows [0:64)=r, [64:128)=z, [128:192)=n
__global__ __launch_bounds__(256)
void k_gru(const float* __restrict__ m_agg, const float* __restrict__ h,
           const float* __restrict__ W_ih, const float* __restrict__ W_hh,
           const float* __restrict__ b_ih, const float* __restrict__ b_hh,
           float* __restrict__ h_out) {
    __shared__ __align__(16) float sm[4*64];
    __shared__ __align__(16) float sh[4*64];
    int t = threadIdx.x;
    int nl = t >> 6, i = t & 63;
    int n = blockIdx.x*4 + nl;
    int nc = (n < NN) ? n : NN-1;
    sm[t] = m_agg[nc*64 + i];
    sh[t] = h[nc*64 + i];
    __syncthreads();
    float air = b_ih[i],     ahr = b_hh[i];
    float aiz = b_ih[64+i],  ahz = b_hh[64+i];
    float ain = b_ih[128+i], ahn = b_hh[128+i];
    const float4* wir = (const float4*)(W_ih + i*64);
    const float4* wiz = (const float4*)(W_ih + (64+i)*64);
    const float4* win = (const float4*)(W_ih + (128+i)*64);
    const float4* whr = (const float4*)(W_hh + i*64);
    const float4* whz = (const float4*)(W_hh + (64+i)*64);
    const float4* whn = (const float4*)(W_hh + (128+i)*64);
    const float4* m4 = (const float4*)(sm + nl*64);
    const float4* h4 = (const float4*)(sh + nl*64);
    #pragma unroll
    for (int q = 0; q < 16; q++) {
        float4 mv = m4[q], hv = h4[q];
        air += dot4(mv, wir[q]);  aiz += dot4(mv, wiz[q]);  ain += dot4(mv, win[q]);
        ahr += dot4(hv, whr[q]);  ahz += dot4(hv, whz[q]);  ahn += dot4(hv, whn[q]);
    }
    float r  = 1.f/(1.f + expf(-(air+ahr)));
    float zg = 1.f/(1.f + expf(-(aiz+ahz)));
    float ng = tanhf(ain + r*ahn);
    if (n < NN) h_out[n*64+i] = (1.f - zg)*ng + zg*sh[t];
}

__global__ void k_scatter_g(const float* __restrict__ h, const int* __restrict__ batch,
                            float* __restrict__ g) {
    int idx = blockIdx.x*256 + threadIdx.x;
    if (idx >= NN*64) return;
    int n = idx >> 6;
    atomicAdd(&g[batch[n]*64 + (idx & 63)], h[idx]);
}

__global__ __launch_bounds__(1024)
void k_readout(const float* __restrict__ g, const float* __restrict__ W1, const float* __restrict__ b1,
               const float* __restrict__ W2, const float* __restrict__ b2, float* __restrict__ out) {
    __shared__ float gs[64*64];
    __shared__ float ts[64*64];
    int t = threadIdx.x;
    for (int idx = t; idx < 4096; idx += 1024) gs[idx] = g[idx];
    __syncthreads();
    for (int idx = t; idx < 4096; idx += 1024) {
        int r = idx >> 6, c = idx & 63;
        float acc = b1[c];
        #pragma unroll 8
        for (int k = 0; k < 64; k++) acc += gs[r*64+k]*W1[k*64+c];
        ts[idx] = fmaxf(acc, 0.f);
    }
    __syncthreads();
    for (int idx = t; idx < 2048; idx += 1024) {
        int r = idx >> 5, c = idx & 31;
        float acc = b2[c];
        #pragma unroll 8
        for (int k = 0; k < 64; k++) acc += ts[r*64+k]*W2[k*32+c];
        out[idx] = acc;
    }
}

extern "C" void kernel_launch(void* const* d_in, const int* in_sizes, int n_in,
                              void* d_out, int out_size, void* d_ws, size_t ws_size,
                              hipStream_t stream) {
    const float* x     = (const float*)d_in[0];
    const int*   ei    = (const int*)  d_in[1];
    const float* ea    = (const float*)d_in[2];
    const int*   batch = (const int*)  d_in[3];
    const float* W_enc = (const float*)d_in[4];
    const float* b_enc = (const float*)d_in[5];
    const float* W_e1  = (const float*)d_in[6];
    const float* b_e1  = (const float*)d_in[7];
    const float* W_e2  = (const float*)d_in[8];
    const float* b_e2  = (const float*)d_in[9];
    const float* W_ih  = (const float*)d_in[10];
    const float* W_hh  = (const float*)d_in[11];
    const float* b_ih  = (const float*)d_in[12];
    const float* b_hh  = (const float*)d_in[13];
    const float* W_r1  = (const float*)d_in[14];
    const float* b_r1  = (const float*)d_in[15];
    const float* W_r2  = (const float*)d_in[16];
    const float* b_r2  = (const float*)d_in[17];
    float* out = (float*)d_out;

    float* ws   = (float*)d_ws;
    float* h    = ws;                   // NN*64
    float* h2   = h    + NN*64;         // NN*64
    float* magg = h2   + NN*64;         // NN*64
    float* z    = magg + NN*64;         // NE*65
    float* W2x  = z    + NE*ZK;         // 4160*64
    float* g    = W2x  + KTOT*64;       // 64*64

    hipLaunchKernelGGL(k_build_w2x, dim3((KTOT*64+255)/256), dim3(256), 0, stream, W_e2, b_e2, W2x);
    hipLaunchKernelGGL(k_encode,    dim3((NN*64+255)/256),   dim3(256), 0, stream, x, W_enc, b_enc, h);
    hipLaunchKernelGGL(k_edgez,     dim3((NE*64+255)/256),   dim3(256), 0, stream, ea, W_e1, b_e1, z);

    float* hc = h; float* hn = h2;
    for (int s = 0; s < 3; s++) {
        hipMemsetAsync(magg, 0, (size_t)NN*64*sizeof(float), stream);
        hipLaunchKernelGGL(k_message, dim3((NE+63)/64), dim3(256), 0, stream, z, hc, ei, W2x, magg);
        hipLaunchKernelGGL(k_gru,     dim3((NN+3)/4),   dim3(256), 0, stream, magg, hc, W_ih, W_hh, b_ih, b_hh, hn);
        float* tmp = hc; hc = hn; hn = tmp;
    }

    hipMemsetAsync(g, 0, (size_t)NG*64*sizeof(float), stream);
    hipLaunchKernelGGL(k_scatter_g, dim3((NN*64+255)/256), dim3(256), 0, stream, hc, batch, g);
    hipLaunchKernelGGL(k_readout,   dim3(1), dim3(1024), 0, stream, g, W_r1, b_r1, W_r2, b_r2, out);
}

// Round 2
// 1008.789 us; speedup vs baseline: 5.2923x; 5.2923x over previous
//
#include <hip/hip_runtime.h>
#include <hip/hip_bf16.h>
#include <math.h>

#define NN 50000
#define NE 100000
#define FN 128
#define FE 16
#define HD 64
#define OUTD 32
#define NG 64
#define ZK 65           // 64 edge-MLP features + 1 bias slot (z=1)

typedef unsigned int uint;
typedef unsigned short ushort;
typedef __attribute__((ext_vector_type(8))) short short8;
typedef __attribute__((ext_vector_type(16))) float f32x16;

static __device__ __forceinline__ float bfbits2f(uint u) {
    return __builtin_bit_cast(float, u << 16);
}
static __device__ __forceinline__ uint packbf(float f0, float f1) {
    // truncate-to-bf16 pack (bias ~2^-9, fine for 1.1 abs threshold)
    uint a = __builtin_bit_cast(uint, f0), b = __builtin_bit_cast(uint, f1);
    return (b & 0xFFFF0000u) | (a >> 16);
}
static __device__ __forceinline__ ushort f2bf(float f) {
    uint u = __builtin_bit_cast(uint, f);
    u = (u + 0x7FFFu + ((u >> 16) & 1u)) >> 16;   // RNE
    return (ushort)u;
}

// ---- prep: Wtb[k0][i][j] bf16, k0-blocked so each k0 slab is contiguous 8KB ----
__global__ void k_build_wt(const float* __restrict__ W_e2, const float* __restrict__ b_e2,
                           ushort* __restrict__ Wtb) {
    int idx = blockIdx.x * 256 + threadIdx.x;
    if (idx >= ZK * 4096) return;
    int k0 = idx >> 12, r = idx & 4095;
    int i = r >> 6, j = r & 63;
    float v = (k0 < 64) ? W_e2[k0 * 4096 + i * 64 + j] : b_e2[i * 64 + j];
    Wtb[idx] = f2bf(v);
}

// ---- prep: WT[k][c] fp32, c<192 -> W_ih[c][k], else W_hh[c-192][k] ----
__global__ void k_build_wgru(const float* __restrict__ W_ih, const float* __restrict__ W_hh,
                             float* __restrict__ WT) {
    int idx = blockIdx.x * 256 + threadIdx.x;
    if (idx >= 64 * 384) return;
    int k = idx / 384, c = idx - k * 384;
    WT[idx] = (c < 192) ? W_ih[c * 64 + k] : W_hh[(c - 192) * 64 + k];
}

// ---- encoder: h fp32 + hb bf16 ----
__global__ void k_encode(const float* __restrict__ x, const float* __restrict__ W,
                         const float* __restrict__ b, float* __restrict__ h,
                         ushort* __restrict__ hb) {
    int idx = blockIdx.x * 256 + threadIdx.x;
    int o = idx & 63, n = idx >> 6;
    if (n >= NN) return;
    const float* xr = x + n * FN;
    float acc = b[o];
    #pragma unroll 8
    for (int f = 0; f < FN; f++) acc += xr[f] * W[f * 64 + o];
    h[idx] = acc;
    hb[idx] = f2bf(acc);
}

// ---- edge MLP, transposed bf16 output: zbT[k][e] ----
__global__ void k_edgez(const float* __restrict__ ea, const float* __restrict__ W,
                        const float* __restrict__ b, ushort* __restrict__ zbT) {
    int e = blockIdx.x * 256 + threadIdx.x;
    int k = blockIdx.y;
    if (e >= NE) return;
    const float* er = ea + e * FE;
    float acc = b[k];
    #pragma unroll
    for (int f = 0; f < FE; f++) acc += er[f] * W[f * 64 + k];
    zbT[(size_t)k * NE + e] = f2bf(fmaxf(acc, 0.f));
    if (k == 0) zbT[(size_t)64 * NE + e] = f2bf(1.0f);
}

// ---- MFMA message kernel ----
// Block: 256 thr = 4 waves; wave = 64 edges (2 M-tiles of 32), N=64 (2 N-tiles).
// K = 65 k0-slabs x 64 j.  A[m][k0*64+j] = z[e,k0]*h[src[e],j] built in-register.
// B slab (64x64 bf16, 8KB) double-buffered in LDS via global_load_lds w/ XOR swizzle.
__global__ __launch_bounds__(256, 2)
void k_message(const ushort* __restrict__ zbT, const ushort* __restrict__ hb,
               const int* __restrict__ eidx, const ushort* __restrict__ Wtb,
               float* __restrict__ m_agg) {
    __shared__ __align__(16) ushort wlds[2][4096];   // 2 x 8KB
    __shared__ int sdst[256];

    int t = threadIdx.x;
    int wave = t >> 6, lane = t & 63;
    int l31 = lane & 31, lhi = lane >> 5;            // lhi in {0,1}
    int eblk = blockIdx.x * 256;
    int e0 = eblk + wave * 64;

    // dst cache
    {
        int e = eblk + t; if (e >= NE) e = NE - 1;
        sdst[t] = eidx[NE + e];
    }

    // gather h fragments (fp32 in regs): hf[mt][c*8+jj] = h[src[e_mt]][c*16+lhi*8+jj]
    float hf[2][32];
    int evalid[2];
    #pragma unroll
    for (int mt = 0; mt < 2; mt++) {
        int e = e0 + mt * 32 + l31;
        evalid[mt] = (e < NE);
        int ec = evalid[mt] ? e : NE - 1;
        int s = eidx[ec];
        const ushort* hrow = hb + s * 64;
        #pragma unroll
        for (int c = 0; c < 4; c++) {
            uint4 v = *(const uint4*)(hrow + c * 16 + lhi * 8);
            hf[mt][c * 8 + 0] = bfbits2f(v.x & 0xFFFFu); hf[mt][c * 8 + 1] = bfbits2f(v.x >> 16);
            hf[mt][c * 8 + 2] = bfbits2f(v.y & 0xFFFFu); hf[mt][c * 8 + 3] = bfbits2f(v.y >> 16);
            hf[mt][c * 8 + 4] = bfbits2f(v.z & 0xFFFFu); hf[mt][c * 8 + 5] = bfbits2f(v.z >> 16);
            hf[mt][c * 8 + 6] = bfbits2f(v.w & 0xFFFFu); hf[mt][c * 8 + 7] = bfbits2f(v.w >> 16);
        }
    }

    // B staging: 512 slots of 16B per slab; wave w covers slots [w*128, w*128+128)
    auto stage = [&](int k0, int buf) {
        const ushort* wt = Wtb + k0 * 4096;
        #pragma unroll
        for (int call = 0; call < 2; call++) {
            int slot = wave * 128 + call * 64 + lane;
            int i = slot >> 3, jbp = slot & 7;
            int jbg = jbp ^ (i & 7);                  // inverse swizzle on global side
            const ushort* src = wt + i * 64 + jbg * 8;
            __builtin_amdgcn_global_load_lds(
                (const __attribute__((address_space(1))) void*)src,
                (__attribute__((address_space(3))) void*)&wlds[buf][(wave * 128 + call * 64) * 8],
                16, 0, 0);
        }
    };

    auto loadz = [&](int k0, int mt) -> float {
        int e = e0 + mt * 32 + l31;
        if (e >= NE) return 0.f;
        return bfbits2f((uint)zbT[(size_t)k0 * NE + e]);
    };

    f32x16 acc00 = {0}, acc01 = {0}, acc10 = {0}, acc11 = {0};
    float zc0 = loadz(0, 0), zc1 = loadz(0, 1);
    stage(0, 0);

    for (int k0 = 0; k0 < ZK; k0++) {
        __syncthreads();                              // slab k0 ready in buf (vmcnt drained)
        int buf = k0 & 1;
        float zn0 = 0.f, zn1 = 0.f;
        if (k0 + 1 < ZK) {
            stage(k0 + 1, buf ^ 1);                   // prefetch next slab
            zn0 = loadz(k0 + 1, 0);
            zn1 = loadz(k0 + 1, 1);
        }
        float zf0 = zc0, zf1 = zc1;
        #pragma unroll
        for (int c = 0; c < 4; c++) {
            int jb = c * 2 + lhi;
            const short8* bp0 = (const short8*)&wlds[buf][((0 * 32 + l31) << 6) + ((jb ^ (l31 & 7)) << 3)];
            const short8* bp1 = (const short8*)&wlds[buf][((32 + l31) << 6) + ((jb ^ (l31 & 7)) << 3)];
            short8 b0 = *bp0, b1 = *bp1;
            uint4 au0, au1;
            au0.x = packbf(zf0 * hf[0][c * 8 + 0], zf0 * hf[0][c * 8 + 1]);
            au0.y = packbf(zf0 * hf[0][c * 8 + 2], zf0 * hf[0][c * 8 + 3]);
            au0.z = packbf(zf0 * hf[0][c * 8 + 4], zf0 * hf[0][c * 8 + 5]);
            au0.w = packbf(zf0 * hf[0][c * 8 + 6], zf0 * hf[0][c * 8 + 7]);
            au1.x = packbf(zf1 * hf[1][c * 8 + 0], zf1 * hf[1][c * 8 + 1]);
            au1.y = packbf(zf1 * hf[1][c * 8 + 2], zf1 * hf[1][c * 8 + 3]);
            au1.z = packbf(zf1 * hf[1][c * 8 + 4], zf1 * hf[1][c * 8 + 5]);
            au1.w = packbf(zf1 * hf[1][c * 8 + 6], zf1 * hf[1][c * 8 + 7]);
            short8 a0 = __builtin_bit_cast(short8, au0);
            short8 a1 = __builtin_bit_cast(short8, au1);
            acc00 = __builtin_amdgcn_mfma_f32_32x32x16_bf16(a0, b0, acc00, 0, 0, 0);
            acc01 = __builtin_amdgcn_mfma_f32_32x32x16_bf16(a0, b1, acc01, 0, 0, 0);
            acc10 = __builtin_amdgcn_mfma_f32_32x32x16_bf16(a1, b0, acc10, 0, 0, 0);
            acc11 = __builtin_amdgcn_mfma_f32_32x32x16_bf16(a1, b1, acc11, 0, 0, 0);
        }
        zc0 = zn0; zc1 = zn1;
    }

    // epilogue: D row = (r&3)+8*(r>>2)+4*lhi (edge-local), col = l31 (+32*nt)
    #pragma unroll
    for (int r = 0; r < 16; r++) {
        int roff = (r & 3) + 8 * (r >> 2) + 4 * lhi;
        int d0 = sdst[wave * 64 + roff];
        int d1 = sdst[wave * 64 + 32 + roff];
        atomicAdd(m_agg + d0 * 64 + l31,      acc00[r]);
        atomicAdd(m_agg + d0 * 64 + 32 + l31, acc01[r]);
        atomicAdd(m_agg + d1 * 64 + l31,      acc10[r]);
        atomicAdd(m_agg + d1 * 64 + 32 + l31, acc11[r]);
    }
}

// ---- GRU with transposed (coalesced) weights ----
__global__ __launch_bounds__(256)
void k_gru(const float* __restrict__ m_agg, const float* __restrict__ h,
           const float* __restrict__ WT, const float* __restrict__ b_ih,
           const float* __restrict__ b_hh, float* __restrict__ h_out,
           ushort* __restrict__ hb_out) {
    __shared__ float sm[4 * 64];
    __shared__ float sh[4 * 64];
    int t = threadIdx.x;
    int nl = t >> 6, i = t & 63;
    int n = blockIdx.x * 4 + nl;
    int nc = (n < NN) ? n : NN - 1;
    sm[t] = m_agg[nc * 64 + i];
    sh[t] = h[nc * 64 + i];
    __syncthreads();
    float air = b_ih[i],       ahr = b_hh[i];
    float aiz = b_ih[64 + i],  ahz = b_hh[64 + i];
    float ain = b_ih[128 + i], ahn = b_hh[128 + i];
    const float* smr = sm + nl * 64;
    const float* shr = sh + nl * 64;
    #pragma unroll 4
    for (int k = 0; k < 64; k++) {
        float mk = smr[k], hk = shr[k];
        const float* w = WT + k * 384;
        air += mk * w[i];        aiz += mk * w[64 + i];  ain += mk * w[128 + i];
        ahr += hk * w[192 + i];  ahz += hk * w[256 + i]; ahn += hk * w[320 + i];
    }
    float r  = 1.f / (1.f + expf(-(air + ahr)));
    float zg = 1.f / (1.f + expf(-(aiz + ahz)));
    float ng = tanhf(ain + r * ahn);
    if (n < NN) {
        float hv = (1.f - zg) * ng + zg * shr[i];
        h_out[n * 64 + i] = hv;
        hb_out[n * 64 + i] = f2bf(hv);
    }
}

// ---- readout scatter: batch is sorted -> run-length accumulate, few atomics ----
__global__ __launch_bounds__(256)
void k_scatter_g(const float* __restrict__ h, const int* __restrict__ batch,
                 float* __restrict__ g) {
    int t = threadIdx.x;
    int i = t & 63, sub = t >> 6;
    int n0 = blockIdx.x * 256 + sub * 64;
    if (n0 >= NN) return;
    float acc = 0.f;
    int curg = batch[n0];
    for (int q = 0; q < 64; q++) {
        int n = n0 + q;
        if (n >= NN) break;
        int gq = batch[n];                 // wave-uniform
        if (gq != curg) {
            atomicAdd(&g[curg * 64 + i], acc);
            acc = 0.f; curg = gq;
        }
        acc += h[n * 64 + i];
    }
    atomicAdd(&g[curg * 64 + i], acc);
}

__global__ __launch_bounds__(1024)
void k_readout(const float* __restrict__ g, const float* __restrict__ W1, const float* __restrict__ b1,
               const float* __restrict__ W2, const float* __restrict__ b2, float* __restrict__ out) {
    __shared__ float gs[64 * 64];
    __shared__ float ts[64 * 64];
    int t = threadIdx.x;
    for (int idx = t; idx < 4096; idx += 1024) gs[idx] = g[idx];
    __syncthreads();
    for (int idx = t; idx < 4096; idx += 1024) {
        int r = idx >> 6, c = idx & 63;
        float acc = b1[c];
        #pragma unroll 8
        for (int k = 0; k < 64; k++) acc += gs[r * 64 + k] * W1[k * 64 + c];
        ts[idx] = fmaxf(acc, 0.f);
    }
    __syncthreads();
    for (int idx = t; idx < 2048; idx += 1024) {
        int r = idx >> 5, c = idx & 31;
        float acc = b2[c];
        #pragma unroll 8
        for (int k = 0; k < 64; k++) acc += ts[r * 64 + k] * W2[k * 32 + c];
        out[idx] = acc;
    }
}

extern "C" void kernel_launch(void* const* d_in, const int* in_sizes, int n_in,
                              void* d_out, int out_size, void* d_ws, size_t ws_size,
                              hipStream_t stream) {
    const float* x     = (const float*)d_in[0];
    const int*   ei    = (const int*)  d_in[1];
    const float* ea    = (const float*)d_in[2];
    const int*   batch = (const int*)  d_in[3];
    const float* W_enc = (const float*)d_in[4];
    const float* b_enc = (const float*)d_in[5];
    const float* W_e1  = (const float*)d_in[6];
    const float* b_e1  = (const float*)d_in[7];
    const float* W_e2  = (const float*)d_in[8];
    const float* b_e2  = (const float*)d_in[9];
    const float* W_ih  = (const float*)d_in[10];
    const float* W_hh  = (const float*)d_in[11];
    const float* b_ih  = (const float*)d_in[12];
    const float* b_hh  = (const float*)d_in[13];
    const float* W_r1  = (const float*)d_in[14];
    const float* b_r1  = (const float*)d_in[15];
    const float* W_r2  = (const float*)d_in[16];
    const float* b_r2  = (const float*)d_in[17];
    float* out = (float*)d_out;

    float* ws   = (float*)d_ws;
    float* h    = ws;                        // NN*64 fp32
    float* h2   = h    + NN * 64;            // NN*64 fp32
    float* magg = h2   + NN * 64;            // NN*64 fp32
    float* g    = magg + NN * 64;            // NG*64 fp32
    float* WT   = g    + NG * 64;            // 64*384 fp32
    ushort* hb  = (ushort*)(WT + 64 * 384);  // NN*64 bf16
    ushort* zbT = hb + NN * 64;              // 65*NE bf16
    ushort* Wtb = zbT + (size_t)ZK * NE;     // 65*4096 bf16

    hipLaunchKernelGGL(k_build_wt,   dim3((ZK * 4096 + 255) / 256), dim3(256), 0, stream, W_e2, b_e2, Wtb);
    hipLaunchKernelGGL(k_build_wgru, dim3((64 * 384 + 255) / 256),  dim3(256), 0, stream, W_ih, W_hh, WT);
    hipLaunchKernelGGL(k_encode,     dim3((NN * 64 + 255) / 256),   dim3(256), 0, stream, x, W_enc, b_enc, h, hb);
    hipLaunchKernelGGL(k_edgez,      dim3((NE + 255) / 256, 64),    dim3(256), 0, stream, ea, W_e1, b_e1, zbT);

    float* hc = h; float* hn = h2;
    for (int s = 0; s < 3; s++) {
        hipMemsetAsync(magg, 0, (size_t)NN * 64 * sizeof(float), stream);
        hipLaunchKernelGGL(k_message, dim3((NE + 255) / 256), dim3(256), 0, stream, zbT, hb, ei, Wtb, magg);
        hipLaunchKernelGGL(k_gru,     dim3((NN + 3) / 4),     dim3(256), 0, stream, magg, hc, WT, b_ih, b_hh, hn, hb);
        float* tmp = hc; hc = hn; hn = tmp;
    }

    hipMemsetAsync(g, 0, (size_t)NG * 64 * sizeof(float), stream);
    hipLaunchKernelGGL(k_scatter_g, dim3((NN + 255) / 256), dim3(256), 0, stream, hc, batch, g);
    hipLaunchKernelGGL(k_readout,   dim3(1), dim3(1024), 0, stream, g, W_r1, b_r1, W_r2, b_r2, out);
}

// Round 3
// 525.288 us; speedup vs baseline: 10.1635x; 1.9205x over previous
//
#include <hip/hip_runtime.h>
#include <hip/hip_bf16.h>
#include <math.h>

#define NN 50000
#define NE 100000
#define FN 128
#define FE 16
#define HD 64
#define OUTD 32
#define NG 64
#define ZK 65           // 64 edge-MLP features + 1 bias slot (z=1)

typedef unsigned int uint;
typedef unsigned short ushort;
typedef __attribute__((ext_vector_type(8))) short short8;
typedef __attribute__((ext_vector_type(16))) float f32x16;

static __device__ __forceinline__ float bfbits2f(uint u) {
    return __builtin_bit_cast(float, u << 16);
}
static __device__ __forceinline__ uint packbf(float f0, float f1) {
    // truncate-to-bf16 pack (fast path for the message A-fragments)
    uint a = __builtin_bit_cast(uint, f0), b = __builtin_bit_cast(uint, f1);
    return (b & 0xFFFF0000u) | (a >> 16);
}
static __device__ __forceinline__ ushort f2bf(float f) {
    uint u = __builtin_bit_cast(uint, f);
    u = (u + 0x7FFFu + ((u >> 16) & 1u)) >> 16;   // RNE
    return (ushort)u;
}
static __device__ __forceinline__ uint pack2rne(float f0, float f1) {
    return (uint)f2bf(f0) | ((uint)f2bf(f1) << 16);
}

// ---- prep: Wtb[k0][i][j] bf16, k0-blocked so each k0 slab is contiguous 8KB ----
__global__ void k_build_wt(const float* __restrict__ W_e2, const float* __restrict__ b_e2,
                           ushort* __restrict__ Wtb) {
    int idx = blockIdx.x * 256 + threadIdx.x;
    if (idx >= ZK * 4096) return;
    int k0 = idx >> 12, r = idx & 4095;
    int i = r >> 6, j = r & 63;
    float v = (k0 < 64) ? W_e2[k0 * 4096 + i * 64 + j] : b_e2[i * 64 + j];
    Wtb[idx] = f2bf(v);
}

// ---- prep: GRU B matrix, bf16 [n=256][k=128]
// n = g*64+i:  g0: r_sum  (k<64: W_ih[i][k],      k>=64: W_hh[i][k-64])
//              g1: z_sum  (rows 64+i)
//              g2: i_n    (k<64: W_ih[128+i][k],  k>=64: 0)
//              g3: h_n    (k<64: 0,               k>=64: W_hh[128+i][k-64])
__global__ void k_build_bgru(const float* __restrict__ W_ih, const float* __restrict__ W_hh,
                             ushort* __restrict__ Bg) {
    int idx = blockIdx.x * 256 + threadIdx.x;
    if (idx >= 256 * 128) return;
    int n = idx >> 7, k = idx & 127;
    int g = n >> 6, i = n & 63;
    float v = 0.f;
    if (g == 0)      v = (k < 64) ? W_ih[i * 64 + k]         : W_hh[i * 64 + (k - 64)];
    else if (g == 1) v = (k < 64) ? W_ih[(64 + i) * 64 + k]  : W_hh[(64 + i) * 64 + (k - 64)];
    else if (g == 2) v = (k < 64) ? W_ih[(128 + i) * 64 + k] : 0.f;
    else             v = (k < 64) ? 0.f                      : W_hh[(128 + i) * 64 + (k - 64)];
    Bg[idx] = f2bf(v);
}

// ---- prep: encoder B matrix bf16 [n=64][k=128], Benc[n][k] = W_enc[k*64+n] ----
__global__ void k_build_benc(const float* __restrict__ W_enc, ushort* __restrict__ Be) {
    int idx = blockIdx.x * 256 + threadIdx.x;
    if (idx >= 64 * 128) return;
    int n = idx >> 7, k = idx & 127;
    Be[idx] = f2bf(W_enc[k * 64 + n]);
}

// ---- MFMA encoder: h = x @ W_enc + b_enc.  M=50000, K=128, N=64 ----
__global__ __launch_bounds__(256, 2)
void k_encode(const float* __restrict__ x, const ushort* __restrict__ Be,
              const float* __restrict__ b, float* __restrict__ h,
              ushort* __restrict__ hb) {
    __shared__ __align__(16) ushort blds[64 * 128];   // 16 KB, XOR-swizzled slots
    int t = threadIdx.x;
    int wave = t >> 6, lane = t & 63, l31 = lane & 31, lhi = lane >> 5;
    for (int idx = t; idx < 1024; idx += 256) {       // 1024 slots of 16B
        int n = idx >> 4, p = idx & 15;
        int ssrc = p ^ (n & 15);
        *(uint4*)&blds[idx * 8] = *(const uint4*)&Be[n * 128 + ssrc * 8];
    }
    int node0 = blockIdx.x * 128 + wave * 32;
    int m = node0 + l31;
    int mc = (m < NN) ? m : NN - 1;
    // A-frags: bf16(x[mc][k]), k = ks*16 + lhi*8 + j
    short8 afr[8];
    const float* xr = x + (size_t)mc * 128;
    #pragma unroll
    for (int ks = 0; ks < 8; ks++) {
        float4 v0 = *(const float4*)(xr + ks * 16 + lhi * 8);
        float4 v1 = *(const float4*)(xr + ks * 16 + lhi * 8 + 4);
        uint4 u;
        u.x = pack2rne(v0.x, v0.y); u.y = pack2rne(v0.z, v0.w);
        u.z = pack2rne(v1.x, v1.y); u.w = pack2rne(v1.z, v1.w);
        afr[ks] = __builtin_bit_cast(short8, u);
    }
    __syncthreads();
    #pragma unroll
    for (int ct = 0; ct < 2; ct++) {
        f32x16 acc = {0};
        int n = ct * 32 + l31;
        #pragma unroll
        for (int ks = 0; ks < 8; ks++) {
            int sp = (ks * 2 + lhi) ^ (n & 15);
            short8 bf = *(const short8*)&blds[n * 128 + sp * 8];
            acc = __builtin_amdgcn_mfma_f32_32x32x16_bf16(afr[ks], bf, acc, 0, 0, 0);
        }
        int o = ct * 32 + l31;
        float bias = b[o];
        #pragma unroll
        for (int r = 0; r < 16; r++) {
            int row = (r & 3) + 8 * (r >> 2) + 4 * lhi;
            int node = node0 + row;
            if (node < NN) {
                float v = acc[r] + bias;
                h[node * 64 + o] = v;
                hb[node * 64 + o] = f2bf(v);
            }
        }
    }
}

// ---- edge MLP: one thread per edge, all 64 outputs; transposed bf16 out zbT[k][e] ----
__global__ __launch_bounds__(256)
void k_edgez(const float* __restrict__ ea, const float* __restrict__ W,
             const float* __restrict__ b, ushort* __restrict__ zbT) {
    __shared__ float Ws[16 * 64];
    __shared__ float b1s[64];
    int t = threadIdx.x;
    for (int idx = t; idx < 1024; idx += 256) Ws[idx] = W[idx];
    if (t < 64) b1s[t] = b[t];
    __syncthreads();
    int e = blockIdx.x * 256 + t;
    int ec = (e < NE) ? e : NE - 1;
    float eav[16];
    const float4* ep = (const float4*)(ea + ec * 16);
    #pragma unroll
    for (int q = 0; q < 4; q++) {
        float4 v = ep[q];
        eav[q * 4 + 0] = v.x; eav[q * 4 + 1] = v.y; eav[q * 4 + 2] = v.z; eav[q * 4 + 3] = v.w;
    }
    if (e >= NE) return;
    #pragma unroll 4
    for (int k = 0; k < 64; k++) {
        float acc = b1s[k];
        #pragma unroll
        for (int f = 0; f < 16; f++) acc += eav[f] * Ws[f * 64 + k];
        zbT[(size_t)k * NE + e] = f2bf(fmaxf(acc, 0.f));
    }
    zbT[(size_t)64 * NE + e] = f2bf(1.0f);
}

// ---- MFMA message kernel (unchanged from R2) ----
__global__ __launch_bounds__(256, 2)
void k_message(const ushort* __restrict__ zbT, const ushort* __restrict__ hb,
               const int* __restrict__ eidx, const ushort* __restrict__ Wtb,
               float* __restrict__ m_agg) {
    __shared__ __align__(16) ushort wlds[2][4096];   // 2 x 8KB
    __shared__ int sdst[256];

    int t = threadIdx.x;
    int wave = t >> 6, lane = t & 63;
    int l31 = lane & 31, lhi = lane >> 5;
    int eblk = blockIdx.x * 256;
    int e0 = eblk + wave * 64;

    {
        int e = eblk + t; if (e >= NE) e = NE - 1;
        sdst[t] = eidx[NE + e];
    }

    float hf[2][32];
    #pragma unroll
    for (int mt = 0; mt < 2; mt++) {
        int e = e0 + mt * 32 + l31;
        int ec = (e < NE) ? e : NE - 1;
        int s = eidx[ec];
        const ushort* hrow = hb + s * 64;
        #pragma unroll
        for (int c = 0; c < 4; c++) {
            uint4 v = *(const uint4*)(hrow + c * 16 + lhi * 8);
            hf[mt][c * 8 + 0] = bfbits2f(v.x & 0xFFFFu); hf[mt][c * 8 + 1] = bfbits2f(v.x >> 16);
            hf[mt][c * 8 + 2] = bfbits2f(v.y & 0xFFFFu); hf[mt][c * 8 + 3] = bfbits2f(v.y >> 16);
            hf[mt][c * 8 + 4] = bfbits2f(v.z & 0xFFFFu); hf[mt][c * 8 + 5] = bfbits2f(v.z >> 16);
            hf[mt][c * 8 + 6] = bfbits2f(v.w & 0xFFFFu); hf[mt][c * 8 + 7] = bfbits2f(v.w >> 16);
        }
    }

    auto stage = [&](int k0, int buf) {
        const ushort* wt = Wtb + k0 * 4096;
        #pragma unroll
        for (int call = 0; call < 2; call++) {
            int slot = wave * 128 + call * 64 + lane;
            int i = slot >> 3, jbp = slot & 7;
            int jbg = jbp ^ (i & 7);
            const ushort* src = wt + i * 64 + jbg * 8;
            __builtin_amdgcn_global_load_lds(
                (const __attribute__((address_space(1))) void*)src,
                (__attribute__((address_space(3))) void*)&wlds[buf][(wave * 128 + call * 64) * 8],
                16, 0, 0);
        }
    };

    auto loadz = [&](int k0, int mt) -> float {
        int e = e0 + mt * 32 + l31;
        if (e >= NE) return 0.f;
        return bfbits2f((uint)zbT[(size_t)k0 * NE + e]);
    };

    f32x16 acc00 = {0}, acc01 = {0}, acc10 = {0}, acc11 = {0};
    float zc0 = loadz(0, 0), zc1 = loadz(0, 1);
    stage(0, 0);

    for (int k0 = 0; k0 < ZK; k0++) {
        __syncthreads();
        int buf = k0 & 1;
        float zn0 = 0.f, zn1 = 0.f;
        if (k0 + 1 < ZK) {
            stage(k0 + 1, buf ^ 1);
            zn0 = loadz(k0 + 1, 0);
            zn1 = loadz(k0 + 1, 1);
        }
        float zf0 = zc0, zf1 = zc1;
        #pragma unroll
        for (int c = 0; c < 4; c++) {
            int jb = c * 2 + lhi;
            const short8* bp0 = (const short8*)&wlds[buf][((0 * 32 + l31) << 6) + ((jb ^ (l31 & 7)) << 3)];
            const short8* bp1 = (const short8*)&wlds[buf][((32 + l31) << 6) + ((jb ^ (l31 & 7)) << 3)];
            short8 b0 = *bp0, b1 = *bp1;
            uint4 au0, au1;
            au0.x = packbf(zf0 * hf[0][c * 8 + 0], zf0 * hf[0][c * 8 + 1]);
            au0.y = packbf(zf0 * hf[0][c * 8 + 2], zf0 * hf[0][c * 8 + 3]);
            au0.z = packbf(zf0 * hf[0][c * 8 + 4], zf0 * hf[0][c * 8 + 5]);
            au0.w = packbf(zf0 * hf[0][c * 8 + 6], zf0 * hf[0][c * 8 + 7]);
            au1.x = packbf(zf1 * hf[1][c * 8 + 0], zf1 * hf[1][c * 8 + 1]);
            au1.y = packbf(zf1 * hf[1][c * 8 + 2], zf1 * hf[1][c * 8 + 3]);
            au1.z = packbf(zf1 * hf[1][c * 8 + 4], zf1 * hf[1][c * 8 + 5]);
            au1.w = packbf(zf1 * hf[1][c * 8 + 6], zf1 * hf[1][c * 8 + 7]);
            short8 a0 = __builtin_bit_cast(short8, au0);
            short8 a1 = __builtin_bit_cast(short8, au1);
            acc00 = __builtin_amdgcn_mfma_f32_32x32x16_bf16(a0, b0, acc00, 0, 0, 0);
            acc01 = __builtin_amdgcn_mfma_f32_32x32x16_bf16(a0, b1, acc01, 0, 0, 0);
            acc10 = __builtin_amdgcn_mfma_f32_32x32x16_bf16(a1, b0, acc10, 0, 0, 0);
            acc11 = __builtin_amdgcn_mfma_f32_32x32x16_bf16(a1, b1, acc11, 0, 0, 0);
        }
        zc0 = zn0; zc1 = zn1;
    }

    #pragma unroll
    for (int r = 0; r < 16; r++) {
        int roff = (r & 3) + 8 * (r >> 2) + 4 * lhi;
        int d0 = sdst[wave * 64 + roff];
        int d1 = sdst[wave * 64 + 32 + roff];
        atomicAdd(m_agg + d0 * 64 + l31,      acc00[r]);
        atomicAdd(m_agg + d0 * 64 + 32 + l31, acc01[r]);
        atomicAdd(m_agg + d1 * 64 + l31,      acc10[r]);
        atomicAdd(m_agg + d1 * 64 + 32 + l31, acc11[r]);
    }
}

// ---- MFMA GRU: [50000, 128]([m|h]) x [128, 256](r,z,in,hn), gates fused in epilogue ----
__global__ __launch_bounds__(256, 2)
void k_gru(const float* __restrict__ magg, const float* __restrict__ h,
           const ushort* __restrict__ hb, const ushort* __restrict__ Bg,
           const float* __restrict__ b_ih, const float* __restrict__ b_hh,
           float* __restrict__ h_out, ushort* __restrict__ hb_out) {
    __shared__ __align__(16) ushort blds[256 * 128];  // 64 KB, XOR-swizzled slots
    int t = threadIdx.x;
    int wave = t >> 6, lane = t & 63, l31 = lane & 31, lhi = lane >> 5;
    for (int idx = t; idx < 4096; idx += 256) {       // 4096 slots of 16B
        int n = idx >> 4, p = idx & 15;
        int ssrc = p ^ (n & 15);
        *(uint4*)&blds[idx * 8] = *(const uint4*)&Bg[n * 128 + ssrc * 8];
    }
    int node0 = blockIdx.x * 128 + wave * 32;
    int m = node0 + l31;
    int mc = (m < NN) ? m : NN - 1;
    // A-frags: k<64 from magg (fp32->bf16 RNE), k>=64 from hb (already bf16)
    short8 afr[8];
    const float* mrow = magg + (size_t)mc * 64;
    #pragma unroll
    for (int ks = 0; ks < 4; ks++) {
        float4 v0 = *(const float4*)(mrow + ks * 16 + lhi * 8);
        float4 v1 = *(const float4*)(mrow + ks * 16 + lhi * 8 + 4);
        uint4 u;
        u.x = pack2rne(v0.x, v0.y); u.y = pack2rne(v0.z, v0.w);
        u.z = pack2rne(v1.x, v1.y); u.w = pack2rne(v1.z, v1.w);
        afr[ks] = __builtin_bit_cast(short8, u);
    }
    const ushort* hrow = hb + (size_t)mc * 64;
    #pragma unroll
    for (int ks = 4; ks < 8; ks++) {
        uint4 v = *(const uint4*)(hrow + (ks - 4) * 16 + lhi * 8);
        afr[ks] = __builtin_bit_cast(short8, v);
    }
    __syncthreads();
    #pragma unroll
    for (int ct = 0; ct < 2; ct++) {
        f32x16 aR = {0}, aZ = {0}, aI = {0}, aH = {0};
        int nR = 0   + ct * 32 + l31;
        int nZ = 64  + ct * 32 + l31;
        int nI = 128 + ct * 32 + l31;
        int nH = 192 + ct * 32 + l31;
        #pragma unroll
        for (int ks = 0; ks < 8; ks++) {
            int s = ks * 2 + lhi;
            short8 a = afr[ks];
            short8 bR = *(const short8*)&blds[nR * 128 + (s ^ (nR & 15)) * 8];
            short8 bZ = *(const short8*)&blds[nZ * 128 + (s ^ (nZ & 15)) * 8];
            short8 bI = *(const short8*)&blds[nI * 128 + (s ^ (nI & 15)) * 8];
            short8 bH = *(const short8*)&blds[nH * 128 + (s ^ (nH & 15)) * 8];
            aR = __builtin_amdgcn_mfma_f32_32x32x16_bf16(a, bR, aR, 0, 0, 0);
            aZ = __builtin_amdgcn_mfma_f32_32x32x16_bf16(a, bZ, aZ, 0, 0, 0);
            aI = __builtin_amdgcn_mfma_f32_32x32x16_bf16(a, bI, aI, 0, 0, 0);
            aH = __builtin_amdgcn_mfma_f32_32x32x16_bf16(a, bH, aH, 0, 0, 0);
        }
        int i = ct * 32 + l31;
        float brv = b_ih[i] + b_hh[i];
        float bzv = b_ih[64 + i] + b_hh[64 + i];
        float biv = b_ih[128 + i];
        float bhv = b_hh[128 + i];
        #pragma unroll
        for (int r = 0; r < 16; r++) {
            int row = (r & 3) + 8 * (r >> 2) + 4 * lhi;
            int node = node0 + row;
            if (node < NN) {
                float ho = h[node * 64 + i];
                float rg = 1.f / (1.f + expf(-(aR[r] + brv)));
                float zg = 1.f / (1.f + expf(-(aZ[r] + bzv)));
                float ng = tanhf(aI[r] + biv + rg * (aH[r] + bhv));
                float hv = (1.f - zg) * ng + zg * ho;
                h_out[node * 64 + i] = hv;
                hb_out[node * 64 + i] = f2bf(hv);
            }
        }
    }
}

// ---- readout scatter: batch sorted -> run-length accumulate ----
__global__ __launch_bounds__(256)
void k_scatter_g(const float* __restrict__ h, const int* __restrict__ batch,
                 float* __restrict__ g) {
    int t = threadIdx.x;
    int i = t & 63, sub = t >> 6;
    int n0 = blockIdx.x * 64 + sub * 16;
    if (n0 >= NN) return;
    float acc = 0.f;
    int curg = batch[n0];
    for (int q = 0; q < 16; q++) {
        int n = n0 + q;
        if (n >= NN) break;
        int gq = batch[n];                 // wave-uniform
        if (gq != curg) {
            atomicAdd(&g[curg * 64 + i], acc);
            acc = 0.f; curg = gq;
        }
        acc += h[n * 64 + i];
    }
    atomicAdd(&g[curg * 64 + i], acc);
}

__global__ __launch_bounds__(1024)
void k_readout(const float* __restrict__ g, const float* __restrict__ W1, const float* __restrict__ b1,
               const float* __restrict__ W2, const float* __restrict__ b2, float* __restrict__ out) {
    __shared__ float gs[64 * 64];
    __shared__ float ts[64 * 64];
    int t = threadIdx.x;
    for (int idx = t; idx < 4096; idx += 1024) gs[idx] = g[idx];
    __syncthreads();
    for (int idx = t; idx < 4096; idx += 1024) {
        int r = idx >> 6, c = idx & 63;
        float acc = b1[c];
        #pragma unroll 8
        for (int k = 0; k < 64; k++) acc += gs[r * 64 + k] * W1[k * 64 + c];
        ts[idx] = fmaxf(acc, 0.f);
    }
    __syncthreads();
    for (int idx = t; idx < 2048; idx += 1024) {
        int r = idx >> 5, c = idx & 31;
        float acc = b2[c];
        #pragma unroll 8
        for (int k = 0; k < 64; k++) acc += ts[r * 64 + k] * W2[k * 32 + c];
        out[idx] = acc;
    }
}

extern "C" void kernel_launch(void* const* d_in, const int* in_sizes, int n_in,
                              void* d_out, int out_size, void* d_ws, size_t ws_size,
                              hipStream_t stream) {
    const float* x     = (const float*)d_in[0];
    const int*   ei    = (const int*)  d_in[1];
    const float* ea    = (const float*)d_in[2];
    const int*   batch = (const int*)  d_in[3];
    const float* W_enc = (const float*)d_in[4];
    const float* b_enc = (const float*)d_in[5];
    const float* W_e1  = (const float*)d_in[6];
    const float* b_e1  = (const float*)d_in[7];
    const float* W_e2  = (const float*)d_in[8];
    const float* b_e2  = (const float*)d_in[9];
    const float* W_ih  = (const float*)d_in[10];
    const float* W_hh  = (const float*)d_in[11];
    const float* b_ih  = (const float*)d_in[12];
    const float* b_hh  = (const float*)d_in[13];
    const float* W_r1  = (const float*)d_in[14];
    const float* b_r1  = (const float*)d_in[15];
    const float* W_r2  = (const float*)d_in[16];
    const float* b_r2  = (const float*)d_in[17];
    float* out = (float*)d_out;

    float* ws    = (float*)d_ws;
    float* h     = ws;                        // NN*64 fp32
    float* h2    = h    + NN * 64;            // NN*64 fp32
    float* magg  = h2   + NN * 64;            // NN*64 fp32
    float* g     = magg + NN * 64;            // NG*64 fp32
    ushort* hb   = (ushort*)(g + NG * 64);    // NN*64 bf16
    ushort* hb2  = hb   + NN * 64;            // NN*64 bf16
    ushort* zbT  = hb2  + NN * 64;            // 65*NE bf16
    ushort* Wtb  = zbT  + (size_t)ZK * NE;    // 65*4096 bf16
    ushort* Bgru = Wtb  + ZK * 4096;          // 256*128 bf16
    ushort* Benc = Bgru + 256 * 128;          // 64*128 bf16

    hipLaunchKernelGGL(k_build_wt,   dim3((ZK * 4096 + 255) / 256), dim3(256), 0, stream, W_e2, b_e2, Wtb);
    hipLaunchKernelGGL(k_build_bgru, dim3(128), dim3(256), 0, stream, W_ih, W_hh, Bgru);
    hipLaunchKernelGGL(k_build_benc, dim3(32),  dim3(256), 0, stream, W_enc, Benc);
    hipLaunchKernelGGL(k_encode,     dim3((NN + 127) / 128), dim3(256), 0, stream, x, Benc, b_enc, h, hb);
    hipLaunchKernelGGL(k_edgez,      dim3((NE + 255) / 256), dim3(256), 0, stream, ea, W_e1, b_e1, zbT);

    float* hc = h;    float* hn = h2;
    ushort* hbc = hb; ushort* hbn = hb2;
    for (int s = 0; s < 3; s++) {
        hipMemsetAsync(magg, 0, (size_t)NN * 64 * sizeof(float), stream);
        hipLaunchKernelGGL(k_message, dim3((NE + 255) / 256), dim3(256), 0, stream, zbT, hbc, ei, Wtb, magg);
        hipLaunchKernelGGL(k_gru,     dim3((NN + 127) / 128), dim3(256), 0, stream, magg, hc, hbc, Bgru, b_ih, b_hh, hn, hbn);
        float* tf = hc; hc = hn; hn = tf;
        ushort* tb = hbc; hbc = hbn; hbn = tb;
    }

    hipMemsetAsync(g, 0, (size_t)NG * 64 * sizeof(float), stream);
    hipLaunchKernelGGL(k_scatter_g, dim3((NN + 63) / 64), dim3(256), 0, stream, hc, batch, g);
    hipLaunchKernelGGL(k_readout,   dim3(1), dim3(1024), 0, stream, g, W_r1, b_r1, W_r2, b_r2, out);
}